// Round 1
// baseline (99.585 us; speedup 1.0000x reference)
//
#include <hip/hip_runtime.h>

// Chamfer distance, B=16, N=M=4096, 2-D fp32 points, prefix-length masks.
// d_out: [fwd 16*4096][bwd 16*4096] fp32.
//
// R7: single fused kernel, query-parallel decomposition.
//  - R6 accounting: 256MiB ws-poison fill (~42us) is the external floor;
//    controllable remainder was ~42us for main+reduce+gaps while pure VALU
//    work is ~5us. The structure (2 dispatches, 16.8MB partial round-trip,
//    cross-XCD partial re-read) was the cost, not the math.
//  - Decompose over QUERIES: block = (row, 128-query chunk) scans the whole
//    valid search prefix via LDS chunks -> final min per query in-register,
//    sqrt+mask+store directly. No partial buffer, no reduce kernel, no
//    atomics/fences (R3 lesson), no grid sync. d_ws entirely unused.
//  - Query-side skip: blocks with qc*128 >= Lq write zeros and exit.
//    Halves expected pair-work vs R6 (which computed all 4096 queries/row).
//  - 1024 blocks x 128 threads (~4/CU, 2 waves) + low VGPR => dynamic
//    balancing of length-skewed rows; row = g&31 so early (always-active)
//    qc=0 blocks of all rows dispatch first, round-robin across CUs.
//  - Inner loop identical math to R6: 2 v_pk_fma_f32 (scalar broadcast) +
//    1 v_min3_f32 per point-pair per query; n=|t|^2 precomputed at staging
//    with 1e30 poison beyond Lp. LDS reads are block-uniform broadcasts
//    (conflict-free). Lp==0 => best stays 1e10, sqrt(1e10+s2)~=1e5 matches
//    ref's sqrt(1e10) to ~1e-4 (absmax budget 2e-3).

#define CHP 512   // pairs per LDS chunk = 1024 points (12 KB LDS)
typedef float f2 __attribute__((ext_vector_type(2)));

__global__ __launch_bounds__(128) void chamfer_fused(
    const float* __restrict__ src, const float* __restrict__ tgt,
    const int* __restrict__ slen, const int* __restrict__ tlen,
    float* __restrict__ out)
{
    __shared__ float4 sh_xy[CHP];  // {x0,x1,y0,y1} per point-pair
    __shared__ f2     sh_n[CHP];   // {|t0|^2, |t1|^2}, 1e30 poison past Lp

    const int g   = blockIdx.x;
    const int tid = threadIdx.x;
    const int row = g & 31;        // interleave rows across consecutive blocks
    const int qc  = g >> 5;        // 32 query-chunks of 128 per row
    const int dir = row >> 4, b = row & 15;

    const int Lq = dir ? tlen[b] : slen[b];   // query-side valid length
    const int Lp = dir ? slen[b] : tlen[b];   // search-side valid length

    const int q = qc * 128 + tid;
    float* op = out + row * 4096;

    if (qc * 128 >= Lq) {          // whole chunk is padded queries -> zeros
        op[q] = 0.f;
        return;
    }

    const float* Q = dir ? tgt : src;
    const float* P = dir ? src : tgt;

    const float2 qv = ((const float2*)Q)[b * 4096 + q];
    const float mx = -2.f * qv.x;
    const float my = -2.f * qv.y;
    const float s2 = fmaf(qv.x, qv.x, qv.y * qv.y);
    float best = 1e10f;            // represents ref's BIG when Lp == 0

    const int npair = (Lp + 1) >> 1;
    const float4* Pp = (const float4*)P + b * 2048;   // pair-packed {x0,y0,x1,y1}

    for (int c0 = 0; c0 < npair; c0 += CHP) {
        const int npc = min(CHP, npair - c0);         // block-uniform
        __syncthreads();                               // protect prev chunk reads
        #pragma unroll
        for (int i = 0; i < 4; ++i) {
            const int p = tid + i * 128;
            if (p < npc) {
                const float4 pp = Pp[c0 + p];
                const int i0 = (c0 + p) * 2;
                const float n0 = (i0 + 0 < Lp) ? fmaf(pp.x, pp.x, pp.y * pp.y) : 1e30f;
                const float n1 = (i0 + 1 < Lp) ? fmaf(pp.z, pp.z, pp.w * pp.w) : 1e30f;
                sh_xy[p] = make_float4(pp.x, pp.z, pp.y, pp.w);  // {x0,x1,y0,y1}
                sh_n[p]  = f2{n0, n1};
            }
        }
        __syncthreads();

        // Per point-pair: 2 v_pk_fma_f32 + 1 v_min3_f32. Uniform j ->
        // broadcast LDS reads, no bank conflicts. min3 chain (4cy) is well
        // under the 10-cycle issue cost per pair -> issue-bound.
        #pragma unroll 8
        for (int j = 0; j < npc; ++j) {
            const float4 xy = sh_xy[j];
            const f2 np = sh_n[j];
            const f2 xp = f2{xy.x, xy.y};
            const f2 yp = f2{xy.z, xy.w};
            f2 v = xp * mx + np;           // pk_fma: n - 2qx*tx
            v = yp * my + v;               // pk_fma: n - 2q.t
            best = fminf(best, fminf(v.x, v.y));       // v_min3_f32
        }
    }

    // d2 = best + s2, clamp, sqrt; padded queries (q >= Lq) -> 0.
    op[q] = (q < Lq) ? sqrtf(fmaxf(best + s2, 0.f)) : 0.f;
}

extern "C" void kernel_launch(void* const* d_in, const int* in_sizes, int n_in,
                              void* d_out, int out_size, void* d_ws, size_t ws_size,
                              hipStream_t stream) {
    const float* src = (const float*)d_in[0];   // [16,4096,2] f32
    const float* tgt = (const float*)d_in[1];   // [16,4096,2] f32
    const int* slen  = (const int*)d_in[2];     // [16] i32
    const int* tlen  = (const int*)d_in[3];     // [16] i32
    (void)d_ws; (void)ws_size;                  // workspace unused (no partials)

    chamfer_fused<<<1024, 128, 0, stream>>>(src, tgt, slen, tlen, (float*)d_out);
}

// Round 2
// 90.286 us; speedup vs baseline: 1.1030x; 1.1030x over previous
//
#include <hip/hip_runtime.h>

// Chamfer distance, B=16, N=M=4096, 2-D fp32 points, prefix-length masks.
// d_out: [fwd 16*4096][bwd 16*4096] fp32.
//
// R8: fused single kernel, balanced 8-wave search-split per block.
//  - R7 post-mortem: fused kernel alone was 46.6us (occupancy 4.8%,
//    VALUBusy 11.5%). Cause 1: NQ=1 query/thread -> 2 ds_reads per 3 VALU
//    ops, ~1 wave/SIMD, LDS latency (~120cy) fully exposed. Cause 2: block
//    duration ~ Lp -> Lp=4096 rows' blocks ran ~2048 serial pair-iters
//    (~20us) and stacked. VALU floor is only ~2.6us; structure was the cost.
//  - R8 decomposition: block = (row, 256-query chunk), 512 threads = 8
//    waves. Waves split the SEARCH prefix (wave w scans its 64-pair slice
//    of each staged 1024-point chunk); each thread carries NQ=4 queries ->
//    24cy VALU per 2 LDS reads (amortized), 16 independent min-chains.
//    Cross-wave combine: sh_best[8][256] LDS reduce (conflict-free,
//    consecutive-lane addressing) -> sqrt+mask+store. No global partials,
//    no atomics/fences (R3 lesson), no second dispatch, d_ws unused.
//  - Active blocks = sum(ceil(Lq/256)) ~ 270-512 of 512 launched -> >=1
//    block/CU, 8 waves/CU = 2/SIMD. Worst block: 2048/8 = 256 pair-iters.
//    Inactive chunk-blocks write zeros and exit (query-side skip, halves
//    pair-work vs computing all 4096 queries/row).
//  - Inner math unchanged (full f32): per pair per query 2 v_pk_fma_f32
//    (scalar op_sel broadcast) + v_min3_f32 = 1.5 instr/point-query.
//    n=|t|^2 poisoned to 1e30 past Lp at staging; Lp==0 -> best 1e10,
//    sqrt(1e10+s2) ~= ref sqrt(1e10) within 2e-4 (absmax budget 2e-3).

#define CHP 512   // pairs per staged chunk = 1024 points (12 KB LDS)
#define NQ  4     // queries per thread
typedef float f2 __attribute__((ext_vector_type(2)));

__global__ __launch_bounds__(512, 2) void chamfer_fused(
    const float* __restrict__ src, const float* __restrict__ tgt,
    const int* __restrict__ slen, const int* __restrict__ tlen,
    float* __restrict__ out)
{
    __shared__ float4 sh_xy[CHP];      // {x0,x1,y0,y1} per point-pair
    __shared__ f2     sh_n[CHP];       // {|t0|^2,|t1|^2}, 1e30 past Lp
    __shared__ float  sh_best[8][256]; // per-wave partial mins (+s2 folded)

    const int g    = blockIdx.x;
    const int tid  = threadIdx.x;
    const int row  = g & 31;           // round-robin rows across blocks
    const int qc   = g >> 5;           // 16 query-chunks of 256 per row
    const int dir  = row >> 4, b = row & 15;
    const int lane = tid & 63, w = tid >> 6;

    const int Lq = dir ? tlen[b] : slen[b];   // query-side valid length
    const int Lp = dir ? slen[b] : tlen[b];   // search-side valid length

    float* op = out + row * 4096 + qc * 256;

    if (qc * 256 >= Lq) {              // whole chunk is padded -> zeros
        if (tid < 256) op[tid] = 0.f;
        return;
    }

    const float* Qp = dir ? tgt : src;
    const float* P  = dir ? src : tgt;

    // NQ=4 queries per thread: lanes of a wave cover queries 0..255 of the
    // chunk; all 8 waves carry the SAME queries over DIFFERENT search slices.
    float mx[NQ], my[NQ], s2q[NQ], best[NQ];
    #pragma unroll
    for (int k = 0; k < NQ; ++k) {
        const int q = qc * 256 + lane + k * 64;
        const float2 qv = ((const float2*)Qp)[b * 4096 + q];
        mx[k] = -2.f * qv.x;
        my[k] = -2.f * qv.y;
        s2q[k] = fmaf(qv.x, qv.x, qv.y * qv.y);
        best[k] = 1e10f;               // == ref's BIG when Lp == 0
    }

    const int npair = (Lp + 1) >> 1;
    const float4* Pp = (const float4*)P + b * 2048;  // pair-packed {x0,y0,x1,y1}

    for (int c0 = 0; c0 < npair; c0 += CHP) {
        const int npc = min(CHP, npair - c0);        // block-uniform
        __syncthreads();                              // protect prev chunk
        if (tid < npc) {
            const float4 pp = Pp[c0 + tid];
            const int i0 = (c0 + tid) * 2;
            const float n0 = (i0 + 0 < Lp) ? fmaf(pp.x, pp.x, pp.y * pp.y) : 1e30f;
            const float n1 = (i0 + 1 < Lp) ? fmaf(pp.z, pp.z, pp.w * pp.w) : 1e30f;
            sh_xy[tid] = make_float4(pp.x, pp.z, pp.y, pp.w);  // {x0,x1,y0,y1}
            sh_n[tid]  = f2{n0, n1};
        }
        __syncthreads();

        // Wave w scans its private 64-pair slice: uniform j -> broadcast
        // LDS reads, conflict-free. Per pair: 2 ds_read amortized over
        // NQ=4 queries x (2 v_pk_fma + v_min3) = 24cy VALU.
        const int j0 = w * 64;
        const int j1 = min(j0 + 64, npc);
        #pragma unroll 8
        for (int j = j0; j < j1; ++j) {
            const float4 xy = sh_xy[j];
            const f2 np = sh_n[j];
            const f2 xp = f2{xy.x, xy.y};
            const f2 yp = f2{xy.z, xy.w};
            #pragma unroll
            for (int k = 0; k < NQ; ++k) {
                f2 v = xp * mx[k] + np;        // pk_fma: n - 2qx*tx
                v = yp * my[k] + v;            // pk_fma: n - 2q.t
                best[k] = fminf(best[k], fminf(v.x, v.y));  // v_min3_f32
            }
        }
    }

    // Fold s2 (uniform per query) and combine the 8 waves' partials.
    #pragma unroll
    for (int k = 0; k < NQ; ++k)
        sh_best[w][lane + k * 64] = best[k] + s2q[k];
    __syncthreads();

    if (tid < 256) {
        float m = sh_best[0][tid];
        #pragma unroll
        for (int ww = 1; ww < 8; ++ww)
            m = fminf(m, sh_best[ww][tid]);
        const int q = qc * 256 + tid;
        op[tid] = (q < Lq) ? sqrtf(fmaxf(m, 0.f)) : 0.f;
    }
}

extern "C" void kernel_launch(void* const* d_in, const int* in_sizes, int n_in,
                              void* d_out, int out_size, void* d_ws, size_t ws_size,
                              hipStream_t stream) {
    const float* src = (const float*)d_in[0];   // [16,4096,2] f32
    const float* tgt = (const float*)d_in[1];   // [16,4096,2] f32
    const int* slen  = (const int*)d_in[2];     // [16] i32
    const int* tlen  = (const int*)d_in[3];     // [16] i32
    (void)d_ws; (void)ws_size;                  // workspace unused

    chamfer_fused<<<512, 512, 0, stream>>>(src, tgt, slen, tlen, (float*)d_out);
}

// Round 3
// 84.723 us; speedup vs baseline: 1.1754x; 1.0657x over previous
//
#include <hip/hip_runtime.h>

// Chamfer distance, B=16, N=M=4096, 2-D fp32 points, prefix-length masks.
// d_out: [fwd 16*4096][bwd 16*4096] fp32.
//
// R9 = R6 (measured best, 84.0us) + query-side work skipping.
//  - R7/R8 post-mortem: both fused single-kernel shapes ran 5-8x above
//    their VALU models (46.6us / ~39us vs predicted 6-10us) with no
//    counter visibility (below the 40us fill in top-5). Reverting to the
//    evidence-anchored two-kernel structure; fused experiments are parked
//    until per-kernel counters are visible again.
//  - Query-skip: reduce masks i >= Lq to 0, so partials for padded queries
//    are dead values. KACT = ceil(Lq/256) is block-uniform -> dispatch a
//    templated scan over KA in {4,8,12,16} (static k-indexing, no scratch;
//    rule #20). Skipped k-slices are neither computed nor stored; garbage
//    ws bytes there are never read (reduce zero-fills i4 >= Lq without
//    touching partials). Expected pair-math and partial traffic x ~0.55.
//  - Everything else identical to R6: 128-pt chunks, 1024/256 grid,
//    launch_bounds(256,2) (no spill), zero atomics/fences (R3 lesson),
//    2 v_pk_fma_f32 + v_min3_f32 per pair per query, full f32
//    (absmax ~2e-3), reduce 256x128 with length-adaptive slice count.

#define NQ 16
typedef float f2 __attribute__((ext_vector_type(2)));

template<int KA>
__device__ __forceinline__ void scan_queries(
    const float* __restrict__ Qrow,          // row base of query cloud
    const float4* __restrict__ sxy, const f2* __restrict__ sn,
    float* __restrict__ slice, int tid)
{
    // KA*64 queries per wave; 4 state VGPRs per query (KA=16 -> ~90 total).
    float mx[KA], my[KA], s2[KA], best[KA];
    #pragma unroll
    for (int k = 0; k < KA; ++k) {
        const float2 q = ((const float2*)Qrow)[tid + k * 256];
        mx[k] = -2.f * q.x;
        my[k] = -2.f * q.y;
        s2[k] = fmaf(q.x, q.x, q.y * q.y);
        best[k] = 3.0e38f;
    }

    // Per point-pair per query: 2 v_pk_fma_f32 (scalar op_sel broadcast)
    // + 1 v_min3_f32; 2 broadcast LDS reads amortized over KA queries.
    #pragma unroll 4
    for (int j = 0; j < 64; ++j) {
        const float4 xy = sxy[j];
        const f2 xp = f2{xy.x, xy.y};
        const f2 yp = f2{xy.z, xy.w};
        const f2 np = sn[j];
        #pragma unroll
        for (int k = 0; k < KA; ++k) {
            f2 v = xp * mx[k] + np;       // pk_fma: n - 2qx*tx
            v = yp * my[k] + v;           // pk_fma: n - 2q.t
            best[k] = fminf(best[k], fminf(v.x, v.y));  // v_min3_f32
        }
    }

    // Plain coalesced stores to this unit's private slice. No atomics.
    #pragma unroll
    for (int k = 0; k < KA; ++k)
        slice[tid + k * 256] = fmaxf(best[k] + s2[k], 0.f);  // clamp commutes with min
}

__global__ __launch_bounds__(256, 2) void chamfer_main(
    const float* __restrict__ src, const float* __restrict__ tgt,
    const int* __restrict__ slen, const int* __restrict__ tlen,
    float* __restrict__ part)   // [32 rows][32 slices][4096] partial mins
{
    __shared__ float4 sh_xy[64];   // {x0,x1,y0,y1} per point-pair
    __shared__ f2     sh_n[64];    // {|t0|^2, |t1|^2}

    const int g   = blockIdx.x;
    const int tid = threadIdx.x;

    // Compacted work lookup: g -> (row, pc). Uniform SALU.
    int row = -1, pc = 0, Lp = 0, acc = 0;
    #pragma unroll
    for (int rr = 0; rr < 32; ++rr) {
        const int L = (rr < 16) ? tlen[rr] : slen[rr - 16];  // search-side length
        const int n = (L + 127) >> 7;                        // active 128-pt chunks
        if (row < 0 && g < acc + n) { row = rr; pc = g - acc; Lp = L; }
        acc += n;
    }
    if (row < 0) return;             // beyond total active units
    const int dir = row >> 4, b = row & 15;

    // Query-side length -> active k-slices (block-uniform).
    const int Lq = dir ? tlen[b] : slen[b];
    const int KACT = (Lq + 255) >> 8;          // 0..16
    if (KACT == 0) return;                     // uniform: no valid queries

    const float* Q = dir ? tgt : src;
    const float* P = dir ? src : tgt;

    // Stage 128 points (64 pairs), pair-packed; poison n for idx >= Lp.
    if (tid < 64) {
        const int base = pc * 128 + tid * 2;
        const float4 pp = ((const float4*)P)[(b * 4096 + base) >> 1];  // {x0,y0,x1,y1}
        const float n0 = (base + 0 < Lp) ? fmaf(pp.x, pp.x, pp.y * pp.y) : 1e30f;
        const float n1 = (base + 1 < Lp) ? fmaf(pp.z, pp.z, pp.w * pp.w) : 1e30f;
        sh_xy[tid] = make_float4(pp.x, pp.z, pp.y, pp.w);    // {x0,x1,y0,y1}
        sh_n[tid]  = f2{n0, n1};
    }
    __syncthreads();

    const float* Qrow = Q + b * 8192;                       // row base (float2 elems)
    float* slice = part + ((size_t)row * 32 + pc) * 4096;

    // Uniform dispatch on rounded-up active query slices. Queries in
    // [Lq, KA*256) are computed wastefully but masked by the reduce.
    switch ((KACT + 3) >> 2) {
        case 1:  scan_queries< 4>(Qrow, sh_xy, sh_n, slice, tid); break;
        case 2:  scan_queries< 8>(Qrow, sh_xy, sh_n, slice, tid); break;
        case 3:  scan_queries<12>(Qrow, sh_xy, sh_n, slice, tid); break;
        default: scan_queries<16>(Qrow, sh_xy, sh_n, slice, tid); break;
    }
}

__global__ __launch_bounds__(128) void chamfer_reduce(
    const float* __restrict__ part,
    const int* __restrict__ slen, const int* __restrict__ tlen,
    float* __restrict__ out)
{
    const int t  = blockIdx.x * 128 + threadIdx.x;   // 32768 threads, 4 elems each
    const int i4 = t * 4;
    const int row = i4 >> 12;                        // dir*16 + b
    const int dir = row >> 4, b = row & 15;
    const int i   = i4 & 4095;
    const int Lq = dir ? tlen[b] : slen[b];
    const int Lp = dir ? slen[b] : tlen[b];

    // Whole float4 in the padded-query region: zero without reading
    // partials (they were never written under query-skip).
    if (i >= Lq) {
        ((float4*)out)[t] = make_float4(0.f, 0.f, 0.f, 0.f);
        return;
    }

    const int nact = (Lp + 127) >> 7;                // active slices (block-uniform)
    float4 best = make_float4(1e10f, 1e10f, 1e10f, 1e10f);
    const float4* p = (const float4*)(part + (size_t)row * 32 * 4096 + i);
    #pragma unroll 4
    for (int s = 0; s < nact; ++s) {
        const float4 v = p[(size_t)s * 1024];        // stride 4096 floats
        best.x = fminf(best.x, v.x);
        best.y = fminf(best.y, v.y);
        best.z = fminf(best.z, v.z);
        best.w = fminf(best.w, v.w);
    }
    float4 r;
    r.x = sqrtf(best.x);                             // i+0 < Lq guaranteed here
    r.y = (i + 1 < Lq) ? sqrtf(best.y) : 0.f;        // nact==0 -> sqrt(1e10), matches ref
    r.z = (i + 2 < Lq) ? sqrtf(best.z) : 0.f;
    r.w = (i + 3 < Lq) ? sqrtf(best.w) : 0.f;
    ((float4*)out)[t] = r;
}

extern "C" void kernel_launch(void* const* d_in, const int* in_sizes, int n_in,
                              void* d_out, int out_size, void* d_ws, size_t ws_size,
                              hipStream_t stream) {
    const float* src = (const float*)d_in[0];   // [16,4096,2] f32
    const float* tgt = (const float*)d_in[1];   // [16,4096,2] f32
    const int* slen  = (const int*)d_in[2];     // [16] i32
    const int* tlen  = (const int*)d_in[3];     // [16] i32
    float* part = (float*)d_ws;                 // 32 x 32 x 4096 f32 = 16.8 MB

    chamfer_main<<<1024, 256, 0, stream>>>(src, tgt, slen, tlen, part);
    chamfer_reduce<<<256, 128, 0, stream>>>(part, slen, tlen, (float*)d_out);
}

// Round 4
// 82.869 us; speedup vs baseline: 1.2017x; 1.0224x over previous
//
#include <hip/hip_runtime.h>

// Chamfer distance, B=16, N=M=4096, 2-D fp32 points, prefix-length masks.
// d_out: [fwd 16*4096][bwd 16*4096] fp32.
//
// R10 = R9 main (unchanged) + latency-tolerant reduce.
//  - R9 post-mortem: 45% work cut was NULL (84.0 -> 84.7). Accounting with
//    R7's directly-measured kernel (46.6us) gives fixed other ~= 12us and
//    OUR kernels ~= 31us vs <10us throughput floor -> latency-bound.
//  - Suspect: reduce at 256x128 = 0.5 waves/SIMD, up to 32 cold-HBM loads
//    per thread at 16KB stride (partials never cache: the 268MB ws fill
//    thrashes L2+L3 every iteration). Session history: R5->R6 attributed
//    ~10us to this re-read path.
//  - New reduce: 512 blocks x 256 threads, block = (row, 256-float seg),
//    slices split 4-ways across waves (<=8 loads/thread, compile-time
//    unrolled, all in flight, wave-uniform predicates), LDS combine of the
//    4 wave-partials, sqrt+mask+float4 store. Exposed latency ~1 round.
//  - Main untouched (one variable per round): query-skip KA in {4,8,12,16},
//    128-pt chunks, 2 v_pk_fma_f32 + v_min3_f32 per pair per query, zero
//    atomics/fences (R3 lesson), full f32 (absmax ~2e-3).

#define NQ 16
typedef float f2 __attribute__((ext_vector_type(2)));

template<int KA>
__device__ __forceinline__ void scan_queries(
    const float* __restrict__ Qrow,          // row base of query cloud
    const float4* __restrict__ sxy, const f2* __restrict__ sn,
    float* __restrict__ slice, int tid)
{
    // KA*64 queries per wave; 4 state VGPRs per query (KA=16 -> ~90 total).
    float mx[KA], my[KA], s2[KA], best[KA];
    #pragma unroll
    for (int k = 0; k < KA; ++k) {
        const float2 q = ((const float2*)Qrow)[tid + k * 256];
        mx[k] = -2.f * q.x;
        my[k] = -2.f * q.y;
        s2[k] = fmaf(q.x, q.x, q.y * q.y);
        best[k] = 3.0e38f;
    }

    // Per point-pair per query: 2 v_pk_fma_f32 (scalar op_sel broadcast)
    // + 1 v_min3_f32; 2 broadcast LDS reads amortized over KA queries.
    #pragma unroll 4
    for (int j = 0; j < 64; ++j) {
        const float4 xy = sxy[j];
        const f2 xp = f2{xy.x, xy.y};
        const f2 yp = f2{xy.z, xy.w};
        const f2 np = sn[j];
        #pragma unroll
        for (int k = 0; k < KA; ++k) {
            f2 v = xp * mx[k] + np;       // pk_fma: n - 2qx*tx
            v = yp * my[k] + v;           // pk_fma: n - 2q.t
            best[k] = fminf(best[k], fminf(v.x, v.y));  // v_min3_f32
        }
    }

    // Plain coalesced stores to this unit's private slice. No atomics.
    #pragma unroll
    for (int k = 0; k < KA; ++k)
        slice[tid + k * 256] = fmaxf(best[k] + s2[k], 0.f);  // clamp commutes with min
}

__global__ __launch_bounds__(256, 2) void chamfer_main(
    const float* __restrict__ src, const float* __restrict__ tgt,
    const int* __restrict__ slen, const int* __restrict__ tlen,
    float* __restrict__ part)   // [32 rows][32 slices][4096] partial mins
{
    __shared__ float4 sh_xy[64];   // {x0,x1,y0,y1} per point-pair
    __shared__ f2     sh_n[64];    // {|t0|^2, |t1|^2}

    const int g   = blockIdx.x;
    const int tid = threadIdx.x;

    // Compacted work lookup: g -> (row, pc). Uniform SALU.
    int row = -1, pc = 0, Lp = 0, acc = 0;
    #pragma unroll
    for (int rr = 0; rr < 32; ++rr) {
        const int L = (rr < 16) ? tlen[rr] : slen[rr - 16];  // search-side length
        const int n = (L + 127) >> 7;                        // active 128-pt chunks
        if (row < 0 && g < acc + n) { row = rr; pc = g - acc; Lp = L; }
        acc += n;
    }
    if (row < 0) return;             // beyond total active units
    const int dir = row >> 4, b = row & 15;

    // Query-side length -> active k-slices (block-uniform).
    const int Lq = dir ? tlen[b] : slen[b];
    const int KACT = (Lq + 255) >> 8;          // 0..16
    if (KACT == 0) return;                     // uniform: no valid queries

    const float* Q = dir ? tgt : src;
    const float* P = dir ? src : tgt;

    // Stage 128 points (64 pairs), pair-packed; poison n for idx >= Lp.
    if (tid < 64) {
        const int base = pc * 128 + tid * 2;
        const float4 pp = ((const float4*)P)[(b * 4096 + base) >> 1];  // {x0,y0,x1,y1}
        const float n0 = (base + 0 < Lp) ? fmaf(pp.x, pp.x, pp.y * pp.y) : 1e30f;
        const float n1 = (base + 1 < Lp) ? fmaf(pp.z, pp.z, pp.w * pp.w) : 1e30f;
        sh_xy[tid] = make_float4(pp.x, pp.z, pp.y, pp.w);    // {x0,x1,y0,y1}
        sh_n[tid]  = f2{n0, n1};
    }
    __syncthreads();

    const float* Qrow = Q + b * 8192;                       // row base (float2 elems)
    float* slice = part + ((size_t)row * 32 + pc) * 4096;

    // Uniform dispatch on rounded-up active query slices. Queries in
    // [Lq, KA*256) are computed wastefully but masked by the reduce.
    switch ((KACT + 3) >> 2) {
        case 1:  scan_queries< 4>(Qrow, sh_xy, sh_n, slice, tid); break;
        case 2:  scan_queries< 8>(Qrow, sh_xy, sh_n, slice, tid); break;
        case 3:  scan_queries<12>(Qrow, sh_xy, sh_n, slice, tid); break;
        default: scan_queries<16>(Qrow, sh_xy, sh_n, slice, tid); break;
    }
}

__global__ __launch_bounds__(256) void chamfer_reduce(
    const float* __restrict__ part,
    const int* __restrict__ slen, const int* __restrict__ tlen,
    float* __restrict__ out)
{
    __shared__ float4 sh[4][64];                 // per-wave partial float4 mins

    const int blk = blockIdx.x;                  // 512 = 32 rows x 16 segments
    const int row = blk >> 4, seg = blk & 15;
    const int dir = row >> 4, b = row & 15;
    const int tid = threadIdx.x;
    const int f4  = tid & 63;                    // float4 index within segment
    const int w   = tid >> 6;                    // wave id = slice quarter

    const int Lq = dir ? tlen[b] : slen[b];
    const int Lp = dir ? slen[b] : tlen[b];

    float4* out4 = (float4*)(out + row * 4096 + seg * 256);

    if (seg * 256 >= Lq) {                       // whole segment padded -> zeros
        if (w == 0) out4[f4] = make_float4(0.f, 0.f, 0.f, 0.f);
        return;
    }

    // Loads below only touch i < ceil(Lq/256)*256 <= KA*256: always written
    // by main under query-skip (never reads ws poison).
    const int nact = (Lp + 127) >> 7;            // 0..32 active slices
    const int nw = min(max(nact - w * 8, 0), 8); // this wave's slice count (uniform)

    const int i = seg * 256 + f4 * 4;            // first float of this float4
    float4 best = make_float4(1e10f, 1e10f, 1e10f, 1e10f);
    const float4* p = (const float4*)(part + ((size_t)row * 32 + w * 8) * 4096 + i);
    #pragma unroll
    for (int j = 0; j < 8; ++j) {                // compile-time unrolled: all
        if (j < nw) {                            // loads issued before waits
            const float4 v = p[(size_t)j * 1024];
            best.x = fminf(best.x, v.x);
            best.y = fminf(best.y, v.y);
            best.z = fminf(best.z, v.z);
            best.w = fminf(best.w, v.w);
        }
    }
    sh[w][f4] = best;
    __syncthreads();

    if (tid < 64) {
        const float4 a = sh[0][tid], c = sh[1][tid], d = sh[2][tid], e = sh[3][tid];
        float4 m;
        m.x = fminf(fminf(a.x, c.x), fminf(d.x, e.x));
        m.y = fminf(fminf(a.y, c.y), fminf(d.y, e.y));
        m.z = fminf(fminf(a.z, c.z), fminf(d.z, e.z));
        m.w = fminf(fminf(a.w, c.w), fminf(d.w, e.w));
        const int ii = seg * 256 + tid * 4;
        float4 r;                                // nact==0 -> sqrt(1e10), matches ref
        r.x = (ii + 0 < Lq) ? sqrtf(fmaxf(m.x, 0.f)) : 0.f;
        r.y = (ii + 1 < Lq) ? sqrtf(fmaxf(m.y, 0.f)) : 0.f;
        r.z = (ii + 2 < Lq) ? sqrtf(fmaxf(m.z, 0.f)) : 0.f;
        r.w = (ii + 3 < Lq) ? sqrtf(fmaxf(m.w, 0.f)) : 0.f;
        out4[tid] = r;
    }
}

extern "C" void kernel_launch(void* const* d_in, const int* in_sizes, int n_in,
                              void* d_out, int out_size, void* d_ws, size_t ws_size,
                              hipStream_t stream) {
    const float* src = (const float*)d_in[0];   // [16,4096,2] f32
    const float* tgt = (const float*)d_in[1];   // [16,4096,2] f32
    const int* slen  = (const int*)d_in[2];     // [16] i32
    const int* tlen  = (const int*)d_in[3];     // [16] i32
    float* part = (float*)d_ws;                 // 32 x 32 x 4096 f32 = 16.8 MB

    chamfer_main<<<1024, 256, 0, stream>>>(src, tgt, slen, tlen, part);
    chamfer_reduce<<<512, 256, 0, stream>>>(part, slen, tlen, (float*)d_out);
}